// Round 2
// baseline (925.754 us; speedup 1.0000x reference)
//
#include <hip/hip_runtime.h>
#include <hip/hip_bf16.h>

#define BATCH 2
#define SEQ   2048
#define DIM   1024
#define HEADS 16
#define DIMH  64

typedef __attribute__((ext_vector_type(8))) short short8;
typedef __attribute__((ext_vector_type(4))) float floatx4;

static __device__ __forceinline__ short8 load8bf(const __hip_bfloat16* p) {
    return *reinterpret_cast<const short8*>(p);
}

// Adaptive A/B fragment load: base interpreted as bf16[] (flag=0) or float[]
// (flag=1); element index is dtype-independent. Returns 8 bf16 (as shorts).
static __device__ __forceinline__ short8 loadAB(const void* base, size_t idx, bool f32) {
    if (!f32) {
        return *reinterpret_cast<const short8*>((const __hip_bfloat16*)base + idx);
    }
    const float* p = (const float*)base + idx;
    floatx4 a = *reinterpret_cast<const floatx4*>(p);
    floatx4 b = *reinterpret_cast<const floatx4*>(p + 4);
    short8 r;
    #pragma unroll
    for (int e = 0; e < 4; ++e) {
        __hip_bfloat16 t0 = __float2bfloat16(a[e]);
        __hip_bfloat16 t1 = __float2bfloat16(b[e]);
        r[e]     = *reinterpret_cast<short*>(&t0);
        r[e + 4] = *reinterpret_cast<short*>(&t1);
    }
    return r;
}

// ---------------------------------------------------------------------------
// Dtype probe: read first 16384 16-bit words of Wq as bf16. True bf16 weights
// have max|v| ~ 0.2; fp32 bits reinterpreted as bf16 hit |v| >> 1e4 with
// overwhelming probability. Writes flag (0=bf16, 1=fp32) into ws.
// ---------------------------------------------------------------------------
__global__ __launch_bounds__(256) void probe_dtype(
    const unsigned short* __restrict__ w, int* __restrict__ flag)
{
    __shared__ float smax[256];
    float mx = 0.f;
    for (int i = threadIdx.x; i < 16384; i += 256) {
        unsigned short u = w[i];
        __hip_bfloat16 h = *reinterpret_cast<__hip_bfloat16*>(&u);
        float f = fabsf(__bfloat162float(h));
        if (!(f < 1.0e4f)) f = 1.0e30f;  // NaN/inf-pattern -> huge
        mx = fmaxf(mx, f);
    }
    smax[threadIdx.x] = mx;
    __syncthreads();
    if (threadIdx.x == 0) {
        float m = 0.f;
        for (int i = 0; i < 256; ++i) m = fmaxf(m, smax[i]);
        *flag = (m > 1.0e4f) ? 1 : 0;
    }
}

// ---------------------------------------------------------------------------
// GEMM (bt): C[M,N] = A[M,K] * W[N,K]^T. 4 waves/block, 64x64 C tile.
// QKV variant writes head-split layout qkv[((b*H+h)*SEQ+n)*DIMH+dv] (bf16).
// ---------------------------------------------------------------------------
__global__ __launch_bounds__(256) void gemm_qkv(
    const void* __restrict__ x,
    const void* __restrict__ Wq,
    const void* __restrict__ Wk,
    const void* __restrict__ Wv,
    __hip_bfloat16* __restrict__ qkv,
    const int* __restrict__ flagp)
{
    const bool f32 = (*flagp != 0);
    const int z = blockIdx.z;
    const void* W = (z == 0) ? Wq : (z == 1) ? Wk : Wv;
    __hip_bfloat16* out = qkv + (size_t)z * (BATCH * SEQ * DIM);

    const int tid  = threadIdx.x;
    const int wv   = tid >> 6;
    const int lane = tid & 63;
    const int quad = lane >> 4;
    const int l16  = lane & 15;
    const int m0   = blockIdx.x * 64 + wv * 16;
    const int n0   = blockIdx.y * 64;

    floatx4 acc[4] = {};
    const size_t abase = (size_t)(m0 + l16) * DIM + quad * 8;
    const size_t bbase = (size_t)(n0 + l16) * DIM + quad * 8;

    for (int k0 = 0; k0 < DIM; k0 += 32) {
        short8 a = loadAB(x, abase + k0, f32);
        #pragma unroll
        for (int ct = 0; ct < 4; ++ct) {
            short8 bf = loadAB(W, bbase + (size_t)ct * 16 * DIM + k0, f32);
            acc[ct] = __builtin_amdgcn_mfma_f32_16x16x32_bf16(a, bf, acc[ct], 0, 0, 0);
        }
    }
    // C/D layout: col = lane&15, row = quad*4 + r  [m89/m91 verified]
    #pragma unroll
    for (int ct = 0; ct < 4; ++ct) {
        const int o = n0 + ct * 16 + l16;
        const int hh = o >> 6, dv = o & 63;
        #pragma unroll
        for (int r = 0; r < 4; ++r) {
            const int m  = m0 + quad * 4 + r;
            const int bb = m >> 11, nn = m & (SEQ - 1);
            out[((size_t)(bb * HEADS + hh) * SEQ + nn) * DIMH + dv] =
                __float2bfloat16(acc[ct][r]);
        }
    }
}

// Output projection: A = omat (always bf16 ws), W = Wo (adaptive),
// C = d_out written as bf16 or fp32 per flag.
__global__ __launch_bounds__(256) void gemm_out(
    const __hip_bfloat16* __restrict__ A,
    const void* __restrict__ W,
    void* __restrict__ C,
    const int* __restrict__ flagp)
{
    const bool f32 = (*flagp != 0);
    const int tid  = threadIdx.x;
    const int wv   = tid >> 6;
    const int lane = tid & 63;
    const int quad = lane >> 4;
    const int l16  = lane & 15;
    const int m0   = blockIdx.x * 64 + wv * 16;
    const int n0   = blockIdx.y * 64;

    floatx4 acc[4] = {};
    const __hip_bfloat16* arow = A + (size_t)(m0 + l16) * DIM + quad * 8;
    const size_t bbase = (size_t)(n0 + l16) * DIM + quad * 8;

    for (int k0 = 0; k0 < DIM; k0 += 32) {
        short8 a = load8bf(arow + k0);
        #pragma unroll
        for (int ct = 0; ct < 4; ++ct) {
            short8 bf = loadAB(W, bbase + (size_t)ct * 16 * DIM + k0, f32);
            acc[ct] = __builtin_amdgcn_mfma_f32_16x16x32_bf16(a, bf, acc[ct], 0, 0, 0);
        }
    }
    #pragma unroll
    for (int ct = 0; ct < 4; ++ct) {
        const int o = n0 + ct * 16 + l16;
        #pragma unroll
        for (int r = 0; r < 4; ++r) {
            const int m = m0 + quad * 4 + r;
            if (f32) ((float*)C)[(size_t)m * DIM + o] = acc[ct][r];
            else ((__hip_bfloat16*)C)[(size_t)m * DIM + o] = __float2bfloat16(acc[ct][r]);
        }
    }
}

// ---------------------------------------------------------------------------
// Causal flash attention (all-bf16 internal). One block per (q64, head, b).
// ---------------------------------------------------------------------------
#define BJ  32
#define KTS 72
#define VTS 40
#define PBS 40

__global__ __launch_bounds__(256) void attn_causal(
    const __hip_bfloat16* __restrict__ qkv,
    __hip_bfloat16* __restrict__ omat)
{
    __shared__ __align__(16) short kt[BJ * KTS];
    __shared__ __align__(16) short vt[DIMH * VTS];
    __shared__ __align__(16) short pb[4][16 * PBS];

    const int b  = blockIdx.z;
    const int h  = blockIdx.y;
    const int q0 = blockIdx.x * 64;
    const size_t hoff = (size_t)(b * HEADS + h) * SEQ * DIMH;
    const size_t one  = (size_t)BATCH * SEQ * DIM;
    const __hip_bfloat16* qb = qkv + hoff;
    const __hip_bfloat16* kb = qkv + one + hoff;
    const __hip_bfloat16* vb = qkv + 2 * one + hoff;

    const int tid  = threadIdx.x;
    const int wv   = tid >> 6;
    const int lane = tid & 63;
    const int quad = lane >> 4;
    const int l16  = lane & 15;

    const int qrow = q0 + wv * 16 + l16;
    short8 aq0 = load8bf(qb + (size_t)qrow * DIMH + quad * 8);
    short8 aq1 = load8bf(qb + (size_t)qrow * DIMH + 32 + quad * 8);

    floatx4 oacc[4] = {};
    float m_i[4], l_i[4];
    #pragma unroll
    for (int r = 0; r < 4; ++r) { m_i[r] = -__builtin_inff(); l_i[r] = 0.f; }

    const int jend = q0 + 64;
    for (int j0 = 0; j0 < jend; j0 += BJ) {
        __syncthreads();
        {
            const int r  = tid >> 3;
            const int c0 = (tid & 7) * 8;
            short8 kk = load8bf(kb + (size_t)(j0 + r) * DIMH + c0);
            *reinterpret_cast<short8*>(&kt[r * KTS + c0]) = kk;
            short8 vvv = load8bf(vb + (size_t)(j0 + r) * DIMH + c0);
            #pragma unroll
            for (int e = 0; e < 8; ++e) vt[(c0 + e) * VTS + r] = vvv[e];
        }
        __syncthreads();

        floatx4 s[2];
        #pragma unroll
        for (int t = 0; t < 2; ++t) {
            short8 bk0 = *reinterpret_cast<const short8*>(&kt[(t * 16 + l16) * KTS + quad * 8]);
            short8 bk1 = *reinterpret_cast<const short8*>(&kt[(t * 16 + l16) * KTS + 32 + quad * 8]);
            floatx4 zz = {};
            zz   = __builtin_amdgcn_mfma_f32_16x16x32_bf16(aq0, bk0, zz, 0, 0, 0);
            s[t] = __builtin_amdgcn_mfma_f32_16x16x32_bf16(aq1, bk1, zz, 0, 0, 0);
        }

        float rowmax[4];
        #pragma unroll
        for (int r = 0; r < 4; ++r) {
            const int ig = q0 + wv * 16 + quad * 4 + r;
            #pragma unroll
            for (int t = 0; t < 2; ++t) {
                const int jg = j0 + t * 16 + l16;
                float val = s[t][r] * 0.125f;
                if (jg > ig) val = -3.0e38f;
                s[t][r] = val;
            }
            rowmax[r] = fmaxf(s[0][r], s[1][r]);
        }
        #pragma unroll
        for (int mk = 1; mk < 16; mk <<= 1) {
            #pragma unroll
            for (int r = 0; r < 4; ++r)
                rowmax[r] = fmaxf(rowmax[r], __shfl_xor(rowmax[r], mk, 64));
        }

        float alpha[4], rsum[4];
        #pragma unroll
        for (int r = 0; r < 4; ++r) {
            const float mn = fmaxf(m_i[r], rowmax[r]);
            alpha[r] = __expf(m_i[r] - mn);
            m_i[r]   = mn;
            const float p0 = __expf(s[0][r] - mn);
            const float p1 = __expf(s[1][r] - mn);
            s[0][r] = p0; s[1][r] = p1;
            rsum[r] = p0 + p1;
        }
        #pragma unroll
        for (int mk = 1; mk < 16; mk <<= 1) {
            #pragma unroll
            for (int r = 0; r < 4; ++r)
                rsum[r] += __shfl_xor(rsum[r], mk, 64);
        }
        #pragma unroll
        for (int r = 0; r < 4; ++r) {
            l_i[r] = l_i[r] * alpha[r] + rsum[r];
            #pragma unroll
            for (int dt = 0; dt < 4; ++dt) oacc[dt][r] *= alpha[r];
        }

        #pragma unroll
        for (int t = 0; t < 2; ++t) {
            #pragma unroll
            for (int r = 0; r < 4; ++r) {
                __hip_bfloat16 pv = __float2bfloat16(s[t][r]);
                pb[wv][(quad * 4 + r) * PBS + t * 16 + l16] = *reinterpret_cast<short*>(&pv);
            }
        }
        short8 ap = *reinterpret_cast<const short8*>(&pb[wv][l16 * PBS + quad * 8]);

        #pragma unroll
        for (int dt = 0; dt < 4; ++dt) {
            short8 bv = *reinterpret_cast<const short8*>(&vt[(dt * 16 + l16) * VTS + quad * 8]);
            oacc[dt] = __builtin_amdgcn_mfma_f32_16x16x32_bf16(ap, bv, oacc[dt], 0, 0, 0);
        }
    }

    #pragma unroll
    for (int dt = 0; dt < 4; ++dt) {
        #pragma unroll
        for (int r = 0; r < 4; ++r) {
            const int ig = q0 + wv * 16 + quad * 4 + r;
            const float ov = oacc[dt][r] / l_i[r];
            omat[(size_t)(b * SEQ + ig) * DIM + h * DIMH + dt * 16 + l16] =
                __float2bfloat16(ov);
        }
    }
}

// ---------------------------------------------------------------------------

extern "C" void kernel_launch(void* const* d_in, const int* in_sizes, int n_in,
                              void* d_out, int out_size, void* d_ws, size_t ws_size,
                              hipStream_t stream) {
    const void* x  = d_in[0];
    const void* Wq = d_in[1];
    const void* Wk = d_in[2];
    const void* Wv = d_in[3];
    const void* Wo = d_in[4];

    // ws layout (bytes): qkv bf16 [0, 25165824) | omat bf16 [25165824, 33554432) | flag int
    __hip_bfloat16* qkv  = (__hip_bfloat16*)d_ws;
    __hip_bfloat16* omat = qkv + (size_t)3 * BATCH * SEQ * DIM;
    int* flagp = (int*)((char*)d_ws + (size_t)33554432);

    probe_dtype<<<1, 256, 0, stream>>>((const unsigned short*)Wq, flagp);
    gemm_qkv  <<<dim3((BATCH * SEQ) / 64, DIM / 64, 3), 256, 0, stream>>>(x, Wq, Wk, Wv, qkv, flagp);
    attn_causal<<<dim3(SEQ / 64, HEADS, BATCH),        256, 0, stream>>>(qkv, omat);
    gemm_out  <<<dim3((BATCH * SEQ) / 64, DIM / 64, 1), 256, 0, stream>>>(omat, Wo, d_out, flagp);
}

// Round 3
// 366.681 us; speedup vs baseline: 2.5247x; 2.5247x over previous
//
#include <hip/hip_runtime.h>
#include <hip/hip_bf16.h>

#define BATCH 2
#define SEQ   2048
#define DIM   1024
#define HEADS 16
#define DIMH  64
#define BK    32

typedef __attribute__((ext_vector_type(8))) short short8;
typedef __attribute__((ext_vector_type(4))) float floatx4;

static __device__ __forceinline__ short8 load8bf(const __hip_bfloat16* p) {
    return *reinterpret_cast<const short8*>(p);
}

static __device__ __forceinline__ short8 pack8(floatx4 a, floatx4 b) {
    short8 r;
    #pragma unroll
    for (int e = 0; e < 4; ++e) {
        __hip_bfloat16 t0 = __float2bfloat16(a[e]);
        __hip_bfloat16 t1 = __float2bfloat16(b[e]);
        r[e]     = *reinterpret_cast<short*>(&t0);
        r[e + 4] = *reinterpret_cast<short*>(&t1);
    }
    return r;
}

static __device__ __forceinline__ void gload_lds16(const void* g, void* l) {
    __builtin_amdgcn_global_load_lds(
        (const __attribute__((address_space(1))) void*)g,
        (__attribute__((address_space(3))) void*)l, 16, 0, 0);
}

// ---------------------------------------------------------------------------
// QKV GEMM, m97 structure: C[4096,1024] = x[4096,1024] * W[1024,1024]^T.
// 128x128 C-tile / block of 256; fp32 tiles staged to LDS via global_load_lds
// (XOR-swizzled chunks: lds_chunk = glb_chunk ^ (row&7) -> 8-acc/bank floor);
// bf16 conversion at frag-read time.  Epilogue writes head-split bf16 qkv.
// ---------------------------------------------------------------------------
__global__ __launch_bounds__(256) void gemm_qkv(
    const float* __restrict__ x,
    const float* __restrict__ Wq,
    const float* __restrict__ Wk,
    const float* __restrict__ Wv,
    __hip_bfloat16* __restrict__ qkv)
{
    __shared__ __align__(16) float As[128 * BK];
    __shared__ __align__(16) float Bs[128 * BK];

    const int z = blockIdx.z;
    const float* W = (z == 0) ? Wq : (z == 1) ? Wk : Wv;
    __hip_bfloat16* out = qkv + (size_t)z * (BATCH * SEQ * DIM);

    const int tid  = threadIdx.x;
    const int wv   = tid >> 6;
    const int lane = tid & 63;
    const int quad = lane >> 4;
    const int l16  = lane & 15;
    const int wm   = wv >> 1, wn = wv & 1;
    const int m0   = blockIdx.x * 128;
    const int n0   = blockIdx.y * 128;

    // staging: thread t covers (row = t>>3 (+32i), lds chunk j = t&7);
    // global chunk = j ^ (row&7)  [swizzle]
    const int srow = tid >> 3;
    const int sg   = (tid & 7) ^ (srow & 7);

    floatx4 acc[4][4] = {};

    for (int k0 = 0; k0 < DIM; k0 += BK) {
        __syncthreads();
        #pragma unroll
        for (int i = 0; i < 4; ++i) {
            const float* ga = x + (size_t)(m0 + srow + i * 32) * DIM + k0 + sg * 4;
            const float* gb = W + (size_t)(n0 + srow + i * 32) * DIM + k0 + sg * 4;
            char* la = (char*)As + i * 4096 + wv * 1024;
            char* lb = (char*)Bs + i * 4096 + wv * 1024;
            gload_lds16(ga, la);
            gload_lds16(gb, lb);
        }
        __syncthreads();

        short8 af[4], bf[4];
        #pragma unroll
        for (int mt = 0; mt < 4; ++mt) {
            const int r  = wm * 64 + mt * 16 + l16;
            const int c0 = (2 * quad) ^ (r & 7);
            const int c1 = (2 * quad + 1) ^ (r & 7);
            floatx4 f0 = *reinterpret_cast<const floatx4*>(&As[r * 32 + c0 * 4]);
            floatx4 f1 = *reinterpret_cast<const floatx4*>(&As[r * 32 + c1 * 4]);
            af[mt] = pack8(f0, f1);
        }
        #pragma unroll
        for (int nt = 0; nt < 4; ++nt) {
            const int r  = wn * 64 + nt * 16 + l16;
            const int c0 = (2 * quad) ^ (r & 7);
            const int c1 = (2 * quad + 1) ^ (r & 7);
            floatx4 f0 = *reinterpret_cast<const floatx4*>(&Bs[r * 32 + c0 * 4]);
            floatx4 f1 = *reinterpret_cast<const floatx4*>(&Bs[r * 32 + c1 * 4]);
            bf[nt] = pack8(f0, f1);
        }
        #pragma unroll
        for (int mt = 0; mt < 4; ++mt)
            #pragma unroll
            for (int nt = 0; nt < 4; ++nt)
                acc[mt][nt] = __builtin_amdgcn_mfma_f32_16x16x32_bf16(
                    af[mt], bf[nt], acc[mt][nt], 0, 0, 0);
    }

    // C/D layout: col = lane&15, row = quad*4 + r  [m89/m91 verified]
    #pragma unroll
    for (int mt = 0; mt < 4; ++mt) {
        #pragma unroll
        for (int nt = 0; nt < 4; ++nt) {
            const int n  = n0 + wn * 64 + nt * 16 + l16;
            const int hh = n >> 6, dv = n & 63;
            #pragma unroll
            for (int r = 0; r < 4; ++r) {
                const int m  = m0 + wm * 64 + mt * 16 + quad * 4 + r;
                const int bb = m >> 11, nn = m & (SEQ - 1);
                out[((size_t)(bb * HEADS + hh) * SEQ + nn) * DIMH + dv] =
                    __float2bfloat16(acc[mt][nt][r]);
            }
        }
    }
}

// ---------------------------------------------------------------------------
// Output projection: C[4096,1024] fp32 = omat(bf16)[4096,1024] * Wo[1024,1024]^T
// A staged bf16 (m97-native layout, bank-optimal); B staged fp32 swizzled.
// ---------------------------------------------------------------------------
__global__ __launch_bounds__(256) void gemm_out(
    const __hip_bfloat16* __restrict__ A,
    const float* __restrict__ W,
    float* __restrict__ C)
{
    __shared__ __align__(16) short Asb[128 * BK];
    __shared__ __align__(16) float Bs[128 * BK];

    const int tid  = threadIdx.x;
    const int wv   = tid >> 6;
    const int lane = tid & 63;
    const int quad = lane >> 4;
    const int l16  = lane & 15;
    const int wm   = wv >> 1, wn = wv & 1;
    const int m0   = blockIdx.x * 128;
    const int n0   = blockIdx.y * 128;

    const int srowA = tid >> 2;              // bf16 A: 64 rows / instr
    const int scolA = (tid & 3) * 8;
    const int srowB = tid >> 3;              // fp32 B: 32 rows / instr
    const int sgB   = (tid & 7) ^ (srowB & 7);

    floatx4 acc[4][4] = {};

    for (int k0 = 0; k0 < DIM; k0 += BK) {
        __syncthreads();
        #pragma unroll
        for (int i = 0; i < 2; ++i) {
            const __hip_bfloat16* ga = A + (size_t)(m0 + srowA + i * 64) * DIM + k0 + scolA;
            gload_lds16(ga, (char*)Asb + i * 4096 + wv * 1024);
        }
        #pragma unroll
        for (int i = 0; i < 4; ++i) {
            const float* gb = W + (size_t)(n0 + srowB + i * 32) * DIM + k0 + sgB * 4;
            gload_lds16(gb, (char*)Bs + i * 4096 + wv * 1024);
        }
        __syncthreads();

        short8 af[4], bf[4];
        #pragma unroll
        for (int mt = 0; mt < 4; ++mt) {
            const int r = wm * 64 + mt * 16 + l16;
            af[mt] = *reinterpret_cast<const short8*>(&Asb[r * 32 + quad * 8]);
        }
        #pragma unroll
        for (int nt = 0; nt < 4; ++nt) {
            const int r  = wn * 64 + nt * 16 + l16;
            const int c0 = (2 * quad) ^ (r & 7);
            const int c1 = (2 * quad + 1) ^ (r & 7);
            floatx4 f0 = *reinterpret_cast<const floatx4*>(&Bs[r * 32 + c0 * 4]);
            floatx4 f1 = *reinterpret_cast<const floatx4*>(&Bs[r * 32 + c1 * 4]);
            bf[nt] = pack8(f0, f1);
        }
        #pragma unroll
        for (int mt = 0; mt < 4; ++mt)
            #pragma unroll
            for (int nt = 0; nt < 4; ++nt)
                acc[mt][nt] = __builtin_amdgcn_mfma_f32_16x16x32_bf16(
                    af[mt], bf[nt], acc[mt][nt], 0, 0, 0);
    }

    #pragma unroll
    for (int mt = 0; mt < 4; ++mt)
        #pragma unroll
        for (int nt = 0; nt < 4; ++nt) {
            const int n = n0 + wn * 64 + nt * 16 + l16;
            #pragma unroll
            for (int r = 0; r < 4; ++r) {
                const int m = m0 + wm * 64 + mt * 16 + quad * 4 + r;
                C[(size_t)m * DIM + n] = acc[mt][nt][r];
            }
        }
}

// ---------------------------------------------------------------------------
// Causal flash attention (unchanged from round 2 — correct; next target).
// ---------------------------------------------------------------------------
#define BJ  32
#define KTS 72
#define VTS 40
#define PBS 40

__global__ __launch_bounds__(256) void attn_causal(
    const __hip_bfloat16* __restrict__ qkv,
    __hip_bfloat16* __restrict__ omat)
{
    __shared__ __align__(16) short kt[BJ * KTS];
    __shared__ __align__(16) short vt[DIMH * VTS];
    __shared__ __align__(16) short pb[4][16 * PBS];

    const int b  = blockIdx.z;
    const int h  = blockIdx.y;
    const int q0 = blockIdx.x * 64;
    const size_t hoff = (size_t)(b * HEADS + h) * SEQ * DIMH;
    const size_t one  = (size_t)BATCH * SEQ * DIM;
    const __hip_bfloat16* qb = qkv + hoff;
    const __hip_bfloat16* kb = qkv + one + hoff;
    const __hip_bfloat16* vb = qkv + 2 * one + hoff;

    const int tid  = threadIdx.x;
    const int wv   = tid >> 6;
    const int lane = tid & 63;
    const int quad = lane >> 4;
    const int l16  = lane & 15;

    const int qrow = q0 + wv * 16 + l16;
    short8 aq0 = load8bf(qb + (size_t)qrow * DIMH + quad * 8);
    short8 aq1 = load8bf(qb + (size_t)qrow * DIMH + 32 + quad * 8);

    floatx4 oacc[4] = {};
    float m_i[4], l_i[4];
    #pragma unroll
    for (int r = 0; r < 4; ++r) { m_i[r] = -__builtin_inff(); l_i[r] = 0.f; }

    const int jend = q0 + 64;
    for (int j0 = 0; j0 < jend; j0 += BJ) {
        __syncthreads();
        {
            const int r  = tid >> 3;
            const int c0 = (tid & 7) * 8;
            short8 kk = load8bf(kb + (size_t)(j0 + r) * DIMH + c0);
            *reinterpret_cast<short8*>(&kt[r * KTS + c0]) = kk;
            short8 vvv = load8bf(vb + (size_t)(j0 + r) * DIMH + c0);
            #pragma unroll
            for (int e = 0; e < 8; ++e) vt[(c0 + e) * VTS + r] = vvv[e];
        }
        __syncthreads();

        floatx4 s[2];
        #pragma unroll
        for (int t = 0; t < 2; ++t) {
            short8 bk0 = *reinterpret_cast<const short8*>(&kt[(t * 16 + l16) * KTS + quad * 8]);
            short8 bk1 = *reinterpret_cast<const short8*>(&kt[(t * 16 + l16) * KTS + 32 + quad * 8]);
            floatx4 zz = {};
            zz   = __builtin_amdgcn_mfma_f32_16x16x32_bf16(aq0, bk0, zz, 0, 0, 0);
            s[t] = __builtin_amdgcn_mfma_f32_16x16x32_bf16(aq1, bk1, zz, 0, 0, 0);
        }

        float rowmax[4];
        #pragma unroll
        for (int r = 0; r < 4; ++r) {
            const int ig = q0 + wv * 16 + quad * 4 + r;
            #pragma unroll
            for (int t = 0; t < 2; ++t) {
                const int jg = j0 + t * 16 + l16;
                float val = s[t][r] * 0.125f;
                if (jg > ig) val = -3.0e38f;
                s[t][r] = val;
            }
            rowmax[r] = fmaxf(s[0][r], s[1][r]);
        }
        #pragma unroll
        for (int mk = 1; mk < 16; mk <<= 1) {
            #pragma unroll
            for (int r = 0; r < 4; ++r)
                rowmax[r] = fmaxf(rowmax[r], __shfl_xor(rowmax[r], mk, 64));
        }

        float alpha[4], rsum[4];
        #pragma unroll
        for (int r = 0; r < 4; ++r) {
            const float mn = fmaxf(m_i[r], rowmax[r]);
            alpha[r] = __expf(m_i[r] - mn);
            m_i[r]   = mn;
            const float p0 = __expf(s[0][r] - mn);
            const float p1 = __expf(s[1][r] - mn);
            s[0][r] = p0; s[1][r] = p1;
            rsum[r] = p0 + p1;
        }
        #pragma unroll
        for (int mk = 1; mk < 16; mk <<= 1) {
            #pragma unroll
            for (int r = 0; r < 4; ++r)
                rsum[r] += __shfl_xor(rsum[r], mk, 64);
        }
        #pragma unroll
        for (int r = 0; r < 4; ++r) {
            l_i[r] = l_i[r] * alpha[r] + rsum[r];
            #pragma unroll
            for (int dt = 0; dt < 4; ++dt) oacc[dt][r] *= alpha[r];
        }

        #pragma unroll
        for (int t = 0; t < 2; ++t) {
            #pragma unroll
            for (int r = 0; r < 4; ++r) {
                __hip_bfloat16 pv = __float2bfloat16(s[t][r]);
                pb[wv][(quad * 4 + r) * PBS + t * 16 + l16] = *reinterpret_cast<short*>(&pv);
            }
        }
        short8 ap = *reinterpret_cast<const short8*>(&pb[wv][l16 * PBS + quad * 8]);

        #pragma unroll
        for (int dt = 0; dt < 4; ++dt) {
            short8 bv = *reinterpret_cast<const short8*>(&vt[(dt * 16 + l16) * VTS + quad * 8]);
            oacc[dt] = __builtin_amdgcn_mfma_f32_16x16x32_bf16(ap, bv, oacc[dt], 0, 0, 0);
        }
    }

    #pragma unroll
    for (int dt = 0; dt < 4; ++dt) {
        #pragma unroll
        for (int r = 0; r < 4; ++r) {
            const int ig = q0 + wv * 16 + quad * 4 + r;
            const float ov = oacc[dt][r] / l_i[r];
            omat[(size_t)(b * SEQ + ig) * DIM + h * DIMH + dt * 16 + l16] =
                __float2bfloat16(ov);
        }
    }
}

// ---------------------------------------------------------------------------

extern "C" void kernel_launch(void* const* d_in, const int* in_sizes, int n_in,
                              void* d_out, int out_size, void* d_ws, size_t ws_size,
                              hipStream_t stream) {
    const float* x  = (const float*)d_in[0];
    const float* Wq = (const float*)d_in[1];
    const float* Wk = (const float*)d_in[2];
    const float* Wv = (const float*)d_in[3];
    const float* Wo = (const float*)d_in[4];

    // ws: qkv bf16 [0, 24M) | omat bf16 [24M, 32M)   (<= proven 33.55 MB)
    __hip_bfloat16* qkv  = (__hip_bfloat16*)d_ws;
    __hip_bfloat16* omat = qkv + (size_t)3 * BATCH * SEQ * DIM;

    gemm_qkv  <<<dim3((BATCH * SEQ) / 128, DIM / 128, 3), 256, 0, stream>>>(x, Wq, Wk, Wv, qkv);
    attn_causal<<<dim3(SEQ / 64, HEADS, BATCH),           256, 0, stream>>>(qkv, omat);
    gemm_out  <<<dim3((BATCH * SEQ) / 128, DIM / 128, 1), 256, 0, stream>>>(omat, Wo, (float*)d_out);
}

// Round 4
// 244.321 us; speedup vs baseline: 3.7891x; 1.5008x over previous
//
#include <hip/hip_runtime.h>
#include <hip/hip_bf16.h>

#define BATCH 2
#define SEQ   2048
#define DIM   1024
#define HEADS 16
#define DIMH  64
#define BK    32
#define LOG2E 1.44269504088896340736f

typedef __attribute__((ext_vector_type(8))) short short8;
typedef __attribute__((ext_vector_type(4))) float floatx4;

static __device__ __forceinline__ short8 pack8(floatx4 a, floatx4 b) {
    short8 r;
    #pragma unroll
    for (int e = 0; e < 4; ++e) {
        __hip_bfloat16 t0 = __float2bfloat16(a[e]);
        __hip_bfloat16 t1 = __float2bfloat16(b[e]);
        r[e]     = *reinterpret_cast<short*>(&t0);
        r[e + 4] = *reinterpret_cast<short*>(&t1);
    }
    return r;
}

static __device__ __forceinline__ void gload_lds16(const void* g, void* l) {
    __builtin_amdgcn_global_load_lds(
        (const __attribute__((address_space(1))) void*)g,
        (__attribute__((address_space(3))) void*)l, 16, 0, 0);
}

// ---------------------------------------------------------------------------
// QKV GEMM (m97 structure).  z==0/1: head-split [b,h,n,dv].  z==2: V written
// TRANSPOSED [b,h,dv,n] so attention can stage V^T with global_load_lds.
// ---------------------------------------------------------------------------
__global__ __launch_bounds__(256) void gemm_qkv(
    const float* __restrict__ x,
    const float* __restrict__ Wq,
    const float* __restrict__ Wk,
    const float* __restrict__ Wv,
    __hip_bfloat16* __restrict__ qkv)
{
    __shared__ __align__(16) float As[128 * BK];
    __shared__ __align__(16) float Bs[128 * BK];

    const int z = blockIdx.z;
    const float* W = (z == 0) ? Wq : (z == 1) ? Wk : Wv;
    __hip_bfloat16* out = qkv + (size_t)z * (BATCH * SEQ * DIM);

    const int tid  = threadIdx.x;
    const int wv   = tid >> 6;
    const int lane = tid & 63;
    const int quad = lane >> 4;
    const int l16  = lane & 15;
    const int wm   = wv >> 1, wn = wv & 1;
    const int m0   = blockIdx.x * 128;
    const int n0   = blockIdx.y * 128;

    const int srow = tid >> 3;
    const int sg   = (tid & 7) ^ (srow & 7);

    floatx4 acc[4][4] = {};

    for (int k0 = 0; k0 < DIM; k0 += BK) {
        __syncthreads();
        #pragma unroll
        for (int i = 0; i < 4; ++i) {
            const float* ga = x + (size_t)(m0 + srow + i * 32) * DIM + k0 + sg * 4;
            const float* gb = W + (size_t)(n0 + srow + i * 32) * DIM + k0 + sg * 4;
            gload_lds16(ga, (char*)As + i * 4096 + wv * 1024);
            gload_lds16(gb, (char*)Bs + i * 4096 + wv * 1024);
        }
        __syncthreads();

        short8 af[4], bf[4];
        #pragma unroll
        for (int mt = 0; mt < 4; ++mt) {
            const int r  = wm * 64 + mt * 16 + l16;
            const int c0 = (2 * quad) ^ (r & 7);
            const int c1 = (2 * quad + 1) ^ (r & 7);
            floatx4 f0 = *reinterpret_cast<const floatx4*>(&As[r * 32 + c0 * 4]);
            floatx4 f1 = *reinterpret_cast<const floatx4*>(&As[r * 32 + c1 * 4]);
            af[mt] = pack8(f0, f1);
        }
        #pragma unroll
        for (int nt = 0; nt < 4; ++nt) {
            const int r  = wn * 64 + nt * 16 + l16;
            const int c0 = (2 * quad) ^ (r & 7);
            const int c1 = (2 * quad + 1) ^ (r & 7);
            floatx4 f0 = *reinterpret_cast<const floatx4*>(&Bs[r * 32 + c0 * 4]);
            floatx4 f1 = *reinterpret_cast<const floatx4*>(&Bs[r * 32 + c1 * 4]);
            bf[nt] = pack8(f0, f1);
        }
        #pragma unroll
        for (int mt = 0; mt < 4; ++mt)
            #pragma unroll
            for (int nt = 0; nt < 4; ++nt)
                acc[mt][nt] = __builtin_amdgcn_mfma_f32_16x16x32_bf16(
                    af[mt], bf[nt], acc[mt][nt], 0, 0, 0);
    }

    #pragma unroll
    for (int mt = 0; mt < 4; ++mt) {
        #pragma unroll
        for (int nt = 0; nt < 4; ++nt) {
            const int n  = n0 + wn * 64 + nt * 16 + l16;
            const int hh = n >> 6, dv = n & 63;
            #pragma unroll
            for (int r = 0; r < 4; ++r) {
                const int m  = m0 + wm * 64 + mt * 16 + quad * 4 + r;
                const int bb = m >> 11, nn = m & (SEQ - 1);
                if (z < 2)
                    out[((size_t)(bb * HEADS + hh) * SEQ + nn) * DIMH + dv] =
                        __float2bfloat16(acc[mt][nt][r]);
                else
                    out[((size_t)(bb * HEADS + hh) * DIMH + dv) * SEQ + nn] =
                        __float2bfloat16(acc[mt][nt][r]);
            }
        }
    }
}

// ---------------------------------------------------------------------------
// Output projection (unchanged): C fp32 = omat(bf16) * Wo^T.
// ---------------------------------------------------------------------------
__global__ __launch_bounds__(256) void gemm_out(
    const __hip_bfloat16* __restrict__ A,
    const float* __restrict__ W,
    float* __restrict__ C)
{
    __shared__ __align__(16) short Asb[128 * BK];
    __shared__ __align__(16) float Bs[128 * BK];

    const int tid  = threadIdx.x;
    const int wv   = tid >> 6;
    const int lane = tid & 63;
    const int quad = lane >> 4;
    const int l16  = lane & 15;
    const int wm   = wv >> 1, wn = wv & 1;
    const int m0   = blockIdx.x * 128;
    const int n0   = blockIdx.y * 128;

    const int srowA = tid >> 2;
    const int scolA = (tid & 3) * 8;
    const int srowB = tid >> 3;
    const int sgB   = (tid & 7) ^ (srowB & 7);

    floatx4 acc[4][4] = {};

    for (int k0 = 0; k0 < DIM; k0 += BK) {
        __syncthreads();
        #pragma unroll
        for (int i = 0; i < 2; ++i) {
            const __hip_bfloat16* ga = A + (size_t)(m0 + srowA + i * 64) * DIM + k0 + scolA;
            gload_lds16(ga, (char*)Asb + i * 4096 + wv * 1024);
        }
        #pragma unroll
        for (int i = 0; i < 4; ++i) {
            const float* gb = W + (size_t)(n0 + srowB + i * 32) * DIM + k0 + sgB * 4;
            gload_lds16(gb, (char*)Bs + i * 4096 + wv * 1024);
        }
        __syncthreads();

        short8 af[4], bf[4];
        #pragma unroll
        for (int mt = 0; mt < 4; ++mt) {
            const int r = wm * 64 + mt * 16 + l16;
            af[mt] = *reinterpret_cast<const short8*>(&Asb[r * 32 + quad * 8]);
        }
        #pragma unroll
        for (int nt = 0; nt < 4; ++nt) {
            const int r  = wn * 64 + nt * 16 + l16;
            const int c0 = (2 * quad) ^ (r & 7);
            const int c1 = (2 * quad + 1) ^ (r & 7);
            floatx4 f0 = *reinterpret_cast<const floatx4*>(&Bs[r * 32 + c0 * 4]);
            floatx4 f1 = *reinterpret_cast<const floatx4*>(&Bs[r * 32 + c1 * 4]);
            bf[nt] = pack8(f0, f1);
        }
        #pragma unroll
        for (int mt = 0; mt < 4; ++mt)
            #pragma unroll
            for (int nt = 0; nt < 4; ++nt)
                acc[mt][nt] = __builtin_amdgcn_mfma_f32_16x16x32_bf16(
                    af[mt], bf[nt], acc[mt][nt], 0, 0, 0);
    }

    #pragma unroll
    for (int mt = 0; mt < 4; ++mt)
        #pragma unroll
        for (int nt = 0; nt < 4; ++nt) {
            const int n = n0 + wn * 64 + nt * 16 + l16;
            #pragma unroll
            for (int r = 0; r < 4; ++r) {
                const int m = m0 + wm * 64 + mt * 16 + quad * 4 + r;
                C[(size_t)m * DIM + n] = acc[mt][nt][r];
            }
        }
}

// ---------------------------------------------------------------------------
// Causal flash attention, transposed formulation.
//   St = K Q^T  (C-layout: col=l16 is the QUERY -> per-lane scalar m/l/alpha)
//   O^T = V^T P^T accumulated in C-layout (col=l16=q, rows=dv)
// BJ=64 keys per step; K and V^T staged via global_load_lds (XOR swizzle);
// P^T round-trips LDS as [q][j] rows (stride 72 -> b128-optimal reads).
// Softmax in log2 domain (exp2f).  q-blocks launched heavy-first.
// ---------------------------------------------------------------------------
__global__ __launch_bounds__(256) void attn_causal(
    const __hip_bfloat16* __restrict__ qkv,
    __hip_bfloat16* __restrict__ omat)
{
    __shared__ __align__(16) short kt[64 * 64];     // [j][k], swizzled chunks
    __shared__ __align__(16) short vt[64 * 64];     // [dv][j], swizzled chunks
    __shared__ __align__(16) short pt[4][16 * 72];  // per-wave [q][j]

    const int b  = blockIdx.z;
    const int h  = blockIdx.y;
    const int q0 = ((int)gridDim.x - 1 - (int)blockIdx.x) * 64;  // heavy first
    const size_t hoff = (size_t)(b * HEADS + h) * SEQ * DIMH;
    const size_t one  = (size_t)BATCH * SEQ * DIM;
    const __hip_bfloat16* qb  = qkv + hoff;             // [n][dv]
    const __hip_bfloat16* kb  = qkv + one + hoff;       // [n][dv]
    const __hip_bfloat16* vtg = qkv + 2 * one + hoff;   // [dv][n] (transposed)

    const int tid  = threadIdx.x;
    const int wv   = tid >> 6;
    const int lane = tid & 63;
    const int quad = lane >> 4;
    const int l16  = lane & 15;

    // Q B-frags: B[k=quad*8+e][n=l16] -> row q = q0+wv*16+l16, contiguous k
    const int qg = q0 + wv * 16 + l16;   // this lane's query index
    short8 aq0 = *reinterpret_cast<const short8*>(qb + (size_t)qg * DIMH + quad * 8);
    short8 aq1 = *reinterpret_cast<const short8*>(qb + (size_t)qg * DIMH + 32 + quad * 8);

    floatx4 oacc[4] = {};
    float m_i = -3.0e38f, l_i = 0.f;

    const int srow = tid >> 3;                 // 0..31
    const int sch  = (tid & 7) ^ (srow & 7);   // XOR-swizzled global chunk
    const int xr   = l16 & 7;                  // frag-read swizzle key

    for (int j0 = 0; j0 < q0 + 64; j0 += 64) {
        __syncthreads();
        #pragma unroll
        for (int i = 0; i < 2; ++i) {
            const __hip_bfloat16* gk = kb  + (size_t)(j0 + srow + i * 32) * DIMH + sch * 8;
            const __hip_bfloat16* gv = vtg + (size_t)(srow + i * 32) * SEQ + j0 + sch * 8;
            gload_lds16(gk, (char*)kt + i * 4096 + wv * 1024);
            gload_lds16(gv, (char*)vt + i * 4096 + wv * 1024);
        }
        __syncthreads();

        // St[j][q] += K[j][k] Q[q][k]
        floatx4 st[4];
        #pragma unroll
        for (int t = 0; t < 4; ++t) {
            const int rw = t * 16 + l16;
            const int c0 = quad ^ xr;
            const int c1 = (quad + 4) ^ xr;
            short8 a0 = *reinterpret_cast<const short8*>(&kt[rw * 64 + c0 * 8]);
            short8 a1 = *reinterpret_cast<const short8*>(&kt[rw * 64 + c1 * 8]);
            floatx4 zz = {};
            zz    = __builtin_amdgcn_mfma_f32_16x16x32_bf16(a0, aq0, zz, 0, 0, 0);
            st[t] = __builtin_amdgcn_mfma_f32_16x16x32_bf16(a1, aq1, st[t] = zz, 0, 0, 0);
        }

        // scale to log2 domain; causal mask (wave-uniform skip when clear)
        const float sc = 0.125f * LOG2E;
        if (j0 + 63 > q0 + wv * 16) {
            #pragma unroll
            for (int t = 0; t < 4; ++t)
                #pragma unroll
                for (int r = 0; r < 4; ++r) {
                    const int jg = j0 + t * 16 + quad * 4 + r;
                    st[t][r] = (jg > qg) ? -3.0e38f : st[t][r] * sc;
                }
        } else {
            #pragma unroll
            for (int t = 0; t < 4; ++t)
                #pragma unroll
                for (int r = 0; r < 4; ++r) st[t][r] *= sc;
        }

        // per-lane softmax state (q = l16 fixed for this lane)
        float mx = m_i;
        #pragma unroll
        for (int t = 0; t < 4; ++t)
            #pragma unroll
            for (int r = 0; r < 4; ++r) mx = fmaxf(mx, st[t][r]);
        mx = fmaxf(mx, __shfl_xor(mx, 16, 64));
        mx = fmaxf(mx, __shfl_xor(mx, 32, 64));

        const float alpha = exp2f(m_i - mx);
        m_i = mx;
        float rs = 0.f;
        #pragma unroll
        for (int t = 0; t < 4; ++t)
            #pragma unroll
            for (int r = 0; r < 4; ++r) {
                const float p = exp2f(st[t][r] - mx);
                st[t][r] = p;
                rs += p;
            }
        rs += __shfl_xor(rs, 16, 64);
        rs += __shfl_xor(rs, 32, 64);
        l_i = l_i * alpha + rs;
        #pragma unroll
        for (int dt = 0; dt < 4; ++dt)
            #pragma unroll
            for (int r = 0; r < 4; ++r) oacc[dt][r] *= alpha;

        // P^T pack: pt[q=l16][j = t*16 + quad*4 + r]
        #pragma unroll
        for (int t = 0; t < 4; ++t)
            #pragma unroll
            for (int r = 0; r < 4; ++r) {
                __hip_bfloat16 pv = __float2bfloat16(st[t][r]);
                pt[wv][l16 * 72 + t * 16 + quad * 4 + r] = *reinterpret_cast<short*>(&pv);
            }
        short8 p0 = *reinterpret_cast<const short8*>(&pt[wv][l16 * 72 + quad * 8]);
        short8 p1 = *reinterpret_cast<const short8*>(&pt[wv][l16 * 72 + 32 + quad * 8]);

        // O^T[dv][q] += V^T[dv][j] P^T[j][q]
        #pragma unroll
        for (int dt = 0; dt < 4; ++dt) {
            const int rw = dt * 16 + l16;
            const int c0 = quad ^ xr;
            const int c1 = (quad + 4) ^ xr;
            short8 v0 = *reinterpret_cast<const short8*>(&vt[rw * 64 + c0 * 8]);
            short8 v1 = *reinterpret_cast<const short8*>(&vt[rw * 64 + c1 * 8]);
            oacc[dt] = __builtin_amdgcn_mfma_f32_16x16x32_bf16(v0, p0, oacc[dt], 0, 0, 0);
            oacc[dt] = __builtin_amdgcn_mfma_f32_16x16x32_bf16(v1, p1, oacc[dt], 0, 0, 0);
        }
    }

    // epilogue: lane's column q=qg; rows are dv = dt*16 + quad*4 + r
    const float rl = 1.0f / l_i;
    #pragma unroll
    for (int dt = 0; dt < 4; ++dt)
        #pragma unroll
        for (int r = 0; r < 4; ++r) {
            const int dv = dt * 16 + quad * 4 + r;
            omat[(size_t)(b * SEQ + qg) * DIM + h * DIMH + dv] =
                __float2bfloat16(oacc[dt][r] * rl);
        }
}

// ---------------------------------------------------------------------------

extern "C" void kernel_launch(void* const* d_in, const int* in_sizes, int n_in,
                              void* d_out, int out_size, void* d_ws, size_t ws_size,
                              hipStream_t stream) {
    const float* x  = (const float*)d_in[0];
    const float* Wq = (const float*)d_in[1];
    const float* Wk = (const float*)d_in[2];
    const float* Wv = (const float*)d_in[3];
    const float* Wo = (const float*)d_in[4];

    __hip_bfloat16* qkv  = (__hip_bfloat16*)d_ws;
    __hip_bfloat16* omat = qkv + (size_t)3 * BATCH * SEQ * DIM;

    gemm_qkv  <<<dim3((BATCH * SEQ) / 128, DIM / 128, 3), 256, 0, stream>>>(x, Wq, Wk, Wv, qkv);
    attn_causal<<<dim3(SEQ / 64, HEADS, BATCH),           256, 0, stream>>>(qkv, omat);
    gemm_out  <<<dim3((BATCH * SEQ) / 128, DIM / 128, 1), 256, 0, stream>>>(omat, Wo, (float*)d_out);
}